// Round 9
// baseline (62.554 us; speedup 1.0000x reference)
//
#include <hip/hip_runtime.h>
#include <math.h>

constexpr int kN = 65536;
constexpr int kB = 16384;
constexpr int kEPB = 8;         // elements per block (one wave)
constexpr int kBlocks = kB / kEPB;          // 2048
constexpr int kTileW = 2560;    // tiered packed triangle words {64,48,32,16}x16
constexpr int kAuxU = 2560;     // U row (64 words)
constexpr int kAuxM = 2624;     // mean row
constexpr int kAuxP = 2688;     // mean_post row
constexpr int kBufW = 2752;     // total words per buffer (11008 B)

static __device__ __forceinline__ float bcastf(float v, int lane) {
    union { float f; int i; } u;
    u.f = v;
    u.i = __builtin_amdgcn_readlane(u.i, lane);
    return u.f;
}

static __device__ __forceinline__ void gload_lds16(const float* g, float* l) {
    __builtin_amdgcn_global_load_lds(
        (const __attribute__((address_space(1))) void*)g,
        (__attribute__((address_space(3))) void*)l, 16, 0, 0);
}
static __device__ __forceinline__ void gload_lds4(const float* g, float* l) {
    __builtin_amdgcn_global_load_lds(
        (const __attribute__((address_space(1))) void*)g,
        (__attribute__((address_space(3))) void*)l, 4, 0, 0);
}

#define CB() asm volatile("" ::: "memory")   // compiler reorder barrier (free)

// tier layout: row j (tier t=j>>4, width w=64-16t) starts at
// off(t) + w*(j-16t), off(t) = 1024t - 128t(t-1)
static __device__ __forceinline__ int row_start(int j) {
    const int t = j >> 4;
    return 1024 * t - 128 * t * (t - 1) + (64 - 16 * t) * (j - 16 * t);
}

static __device__ __forceinline__ bool is_hot(int g) {
    return (g >= 63) && (g <= kN - 63);
}

// Issue ALL of one element's loads. Hot path: EXACTLY 13 VM instructions
// (10 tile + 3 aux rows), nothing else -> counted vmcnt works.
static __device__ __forceinline__ void stage_one(
    int g, int lane, float* buf,
    const float* __restrict__ Uv, const float* __restrict__ Vv,
    const float* __restrict__ mean, const float* __restrict__ mean_post,
    const int* __restrict__ crow_u, const int* __restrict__ crow_v)
{
    if (is_hot(g)) {
        const float* base = Vv + 64 * (g - 63);  // contiguous 16KB row block
        // tier0: rows 0..15 full width (1024 words @ 0)
        {
            const float* src = base + 4 * lane;
            #pragma unroll
            for (int k = 0; k < 4; ++k)
                gload_lds16(src + 256 * k, buf + 256 * k);
        }
        // tier1: rows 16..31, width 48 (768 words @ 1024)
        #pragma unroll
        for (int k = 0; k < 3; ++k) {
            const int w   = 256 * k + 4 * lane;
            const int jj  = ((w >> 4) * 171) >> 9;   // exact (w/16)/3 for w<768
            const int col = w - 48 * jj;
            gload_lds16(base + 64 * (16 + jj) + col, buf + 1024 + 256 * k);
        }
        // tier2: rows 32..47, width 32 (512 words @ 1792)
        #pragma unroll
        for (int k = 0; k < 2; ++k) {
            const int w = 256 * k + 4 * lane;
            gload_lds16(base + 64 * (32 + (w >> 5)) + (w & 31), buf + 1792 + 256 * k);
        }
        // tier3: rows 48..63, width 16 (256 words @ 2304)
        {
            const int w = 4 * lane;
            gload_lds16(base + 64 * (48 + (w >> 4)) + (w & 15), buf + 2304);
        }
        // aux rows (hot: all 64 lanes valid, L=64)
        const int ub = 2016 + 64 * (g - 63);
        gload_lds4(Uv + ub + lane,               buf + kAuxU);
        gload_lds4(mean + (g - 63) + lane,       buf + kAuxM);
        gload_lds4(mean_post + (g - 63) + lane,  buf + kAuxP);
    } else {
        // rare (~32/16384): g<63 (identity rows) or band tail (crow_v irregular)
        const int  anc = g - 63 + lane;
        const bool vl  = (anc >= 0);
        const int  L   = (g + 1 < 64) ? (g + 1) : 64;
        const int  ub  = crow_u[g];
        // zero invalid tile rows + aux slots first, then drain LDS writes,
        // THEN issue DMA (so DMA results land after the zeros).
        for (int j = 0; j < 64; ++j) {
            if ((g - 63 + j) < 0 && lane < 64 - j)
                buf[row_start(j) + lane] = 0.0f;
        }
        buf[kAuxU + lane] = 0.0f;
        buf[kAuxM + lane] = 0.0f;
        buf[kAuxP + lane] = 0.0f;
        asm volatile("s_waitcnt lgkmcnt(0)" ::: "memory");
        int rowbase = 0;
        if (vl) rowbase = crow_v[anc];
        for (int j = 0; j < 64; ++j) {
            const int rbj = __builtin_amdgcn_readlane(rowbase, j);
            if ((g - 63 + j) >= 0 && lane < 64 - j)
                gload_lds4(Vv + rbj + lane, buf + row_start(j));
        }
        if (vl) {
            gload_lds4(Uv + ub + lane - (64 - L), buf + kAuxU);
            gload_lds4(mean + anc,                buf + kAuxM);
            gload_lds4(mean_post + anc,           buf + kAuxP);
        }
    }
}

// Pre-scaled dual-RHS back-substitution on a staged buffer.
// Returns this element's contribution WITHOUT the resid^2 term (hoisted).
static __device__ __forceinline__ float compute_one(
    int g, int lane, const float* buf, float inv2n)
{
    const int  anc = g - 63 + lane;
    const bool vl  = (anc >= 0);

    const int rs = row_start(lane);
    const float d0   = buf[rs];
    const float diag = vl ? d0 : 1.0f;           // identity rows: unit diagonal
    const float invd = 1.0f / diag;

    const float uval = buf[kAuxU + lane];
    const float md   = buf[kAuxM + lane] - buf[kAuxP + lane];

    // v[i] = V_sub[lane][i]/diag for i>=lane; i<lane reads prior rows' garbage,
    // provably unused before this lane's residual is consumed at step i=lane.
    const float* vrow = buf + (rs - lane);
    float v[64];
    #pragma unroll
    for (int i = 0; i < 64; i += 2) {
        const float a0 = vrow[i];
        const float a1 = vrow[i + 1];
        v[i]     = a0 * invd;
        v[i + 1] = a1 * invd;
    }

    float r_e = (lane == 63) ? invd : 0.0f;      // D^-1 e_{63}
    float r_u = uval * invd;                     // D^-1 U_sub
    float acc_e = 0.0f, acc_u = 0.0f;

    #pragma unroll
    for (int i = 63; i >= 0; --i) {
        const float s_e = bcastf(r_e, i);        // x_i for RHS e
        const float s_u = bcastf(r_u, i);        // x_i for RHS u
        r_e = fmaf(-v[i], s_e, r_e);             // on lane i: v[i]=1 -> r=0
        r_u = fmaf(-v[i], s_u, r_u);
        acc_e = fmaf(s_e, s_e, acc_e);
        acc_u = fmaf(s_u, s_u, acc_u);
    }

    float dot = uval * md;
    #pragma unroll
    for (int m = 1; m < 64; m <<= 1)
        dot += __shfl_xor(dot, m, 64);

    const float ulast  = bcastf(uval, 63);       // U_values[crow_u[g+1]-1]
    const float vfirst = bcastf(diag, 63);       // V_values[crow_v[g]]

    return __logf(ulast) - __logf(vfirst)
         - 0.5f * dot * dot
         - 0.5f * acc_u
         - acc_e * inv2n;
}

#define WAIT_HOT()  asm volatile("s_waitcnt vmcnt(13) lgkmcnt(0)" ::: "memory")
#define WAIT_ALL()  asm volatile("s_waitcnt vmcnt(0)  lgkmcnt(0)" ::: "memory")

__global__ __launch_bounds__(64) void gp_solve_kernel(
    const float* __restrict__ Uv,
    const float* __restrict__ Vv,
    const float* __restrict__ mean,
    const float* __restrict__ mean_post,
    const float* __restrict__ y,
    const int*   __restrict__ gidx,
    const int*   __restrict__ crow_u,
    const int*   __restrict__ crow_v,
    const float* __restrict__ noise,
    float*       __restrict__ partial)
{
    __shared__ __align__(16) float bufA[kBufW];
    __shared__ __align__(16) float bufB[kBufW];

    const int lane  = (int)threadIdx.x;
    const int bbase = (int)blockIdx.x * kEPB;

    // ---- prologue: ALL uniform loads up front (oldest VM/SMEM -> any later
    // counted wait safely drains them). Precompute sum of resid^2. ----
    const int g0 = gidx[bbase + 0], g1 = gidx[bbase + 1];
    const int g2 = gidx[bbase + 2], g3 = gidx[bbase + 3];
    const int g4 = gidx[bbase + 4], g5 = gidx[bbase + 5];
    const int g6 = gidx[bbase + 6], g7 = gidx[bbase + 7];
    const float inv2n = 0.5f / noise[0];

    float rsum = 0.0f;
    {
        const float r0 = y[g0] - mean_post[g0], r1 = y[g1] - mean_post[g1];
        const float r2 = y[g2] - mean_post[g2], r3 = y[g3] - mean_post[g3];
        const float r4 = y[g4] - mean_post[g4], r5 = y[g5] - mean_post[g5];
        const float r6 = y[g6] - mean_post[g6], r7 = y[g7] - mean_post[g7];
        rsum = ((r0 * r0 + r1 * r1) + (r2 * r2 + r3 * r3))
             + ((r4 * r4 + r5 * r5) + (r6 * r6 + r7 * r7));
    }
    CB();

    float accum = 0.0f;
    int  gA = g0;
    stage_one(gA, lane, bufA, Uv, Vv, mean, mean_post, crow_u, crow_v);
    CB();

    #pragma unroll 1
    for (int ee = 0; ee < 4; ++ee) {
        // current pair: A = 2ee (in bufA, staged), B = 2ee+1
        const int gB = (ee < 2) ? (ee == 0 ? g1 : g3) : (ee == 2 ? g5 : g7);
        const bool hB = is_hot(gB);
        stage_one(gB, lane, bufB, Uv, Vv, mean, mean_post, crow_u, crow_v);
        CB();
        if (hB) WAIT_HOT(); else WAIT_ALL();   // A's 13 drained, B's 13 in flight
        accum += compute_one(gA, lane, bufA, inv2n);
        CB();

        // next pair's first element C = 2ee+2 -> bufA
        int gC = 0; bool hC = false;
        if (ee < 3) {
            gC = (ee == 0) ? g2 : (ee == 1 ? g4 : g6);
            hC = is_hot(gC);
            stage_one(gC, lane, bufA, Uv, Vv, mean, mean_post, crow_u, crow_v);
            CB();
        }
        if (ee < 3 && hC) WAIT_HOT(); else WAIT_ALL();  // B drained, C in flight
        accum += compute_one(gB, lane, bufB, inv2n);
        CB();
        gA = gC;
    }

    if (lane == 0)
        partial[blockIdx.x] = accum - rsum * inv2n;
}

__global__ __launch_bounds__(512) void gp_reduce_kernel(
    const float* __restrict__ partial,
    const float* __restrict__ noise,
    float*       __restrict__ out)
{
    __shared__ float ws[8];
    const int t = (int)threadIdx.x;
    const float4 p = reinterpret_cast<const float4*>(partial)[t];   // 512*4 = 2048
    float a = (p.x + p.y) + (p.z + p.w);
    #pragma unroll
    for (int m = 1; m < 64; m <<= 1)
        a += __shfl_xor(a, m, 64);
    if ((t & 63) == 0) ws[t >> 6] = a;
    __syncthreads();
    if (t == 0) {
        float tot = 0.0f;
        #pragma unroll
        for (int k = 0; k < 8; ++k) tot += ws[k];
        tot += -0.5f * (float)kB * logf(2.0f * 3.14159265358979323846f * noise[0]);
        out[0] = tot;
    }
}

extern "C" void kernel_launch(void* const* d_in, const int* in_sizes, int n_in,
                              void* d_out, int out_size, void* d_ws, size_t ws_size,
                              hipStream_t stream)
{
    const float* Uv        = (const float*)d_in[0];
    const float* Vv        = (const float*)d_in[1];
    const float* mean      = (const float*)d_in[2];
    const float* mean_post = (const float*)d_in[3];
    const float* y         = (const float*)d_in[4];
    const float* noise     = (const float*)d_in[5];
    const int*   gidx      = (const int*)d_in[6];
    const int*   crow_u    = (const int*)d_in[7];
    const int*   crow_v    = (const int*)d_in[8];
    float* partial = (float*)d_ws;   // kBlocks floats

    gp_solve_kernel<<<dim3(kBlocks), dim3(64), 0, stream>>>(
        Uv, Vv, mean, mean_post, y, gidx, crow_u, crow_v, noise, partial);
    gp_reduce_kernel<<<dim3(1), dim3(512), 0, stream>>>(
        partial, noise, (float*)d_out);
}

// Round 10
// 38.533 us; speedup vs baseline: 1.6234x; 1.6234x over previous
//
#include <hip/hip_runtime.h>
#include <math.h>

constexpr int kN = 65536;
constexpr int kB = 16384;
constexpr int kEPB = 4;                  // elements per wave (pipelined, 1 LDS buffer)
constexpr int kBlocks = kB / kEPB;       // 4096 blocks = 16/CU nominal
constexpr int kTileW = 2560;             // tiered packed triangle {64,48,32,16}x16 rows

static __device__ __forceinline__ float bcastf(float v, int lane) {
    union { float f; int i; } u;
    u.f = v;
    u.i = __builtin_amdgcn_readlane(u.i, lane);
    return u.f;
}

// async global->LDS; LDS dest = wave-uniform base + lane*size (active lanes only)
static __device__ __forceinline__ void gload_lds16(const float* g, float* l) {
    __builtin_amdgcn_global_load_lds(
        (const __attribute__((address_space(1))) void*)g,
        (__attribute__((address_space(3))) void*)l, 16, 0, 0);
}
static __device__ __forceinline__ void gload_lds4(const float* g, float* l) {
    __builtin_amdgcn_global_load_lds(
        (const __attribute__((address_space(1))) void*)g,
        (__attribute__((address_space(3))) void*)l, 4, 0, 0);
}

// tier layout: row j (tier t=j>>4, width w=64-16t) starts at
// off(t) + w*(j-16t), off(t) = 1024t - 128t(t-1)
static __device__ __forceinline__ int row_start(int j) {
    const int t = j >> 4;
    return 1024 * t - 128 * t * (t - 1) + (64 - 16 * t) * (j - 16 * t);
}

static __device__ __forceinline__ bool is_hot(int g) {
    return (g >= 63) && (g <= kN - 63);
}

// Stage one element's packed V tile into LDS. Hot path: 10 DMA ops, no waits.
static __device__ __forceinline__ void stage_tile(
    int g, int lane, float* buf,
    const float* __restrict__ Vv, const int* __restrict__ crow_v)
{
    if (is_hot(g)) {
        const float* base = Vv + 64 * (g - 63);  // contiguous 16KB row block
        // tier0: rows 0..15 full width (1024 words @ 0)
        {
            const float* src = base + 4 * lane;
            #pragma unroll
            for (int k = 0; k < 4; ++k)
                gload_lds16(src + 256 * k, buf + 256 * k);
        }
        // tier1: rows 16..31, width 48 (768 words @ 1024)
        #pragma unroll
        for (int k = 0; k < 3; ++k) {
            const int w   = 256 * k + 4 * lane;
            const int jj  = ((w >> 4) * 171) >> 9;   // exact (w/16)/3 for w<768
            const int col = w - 48 * jj;
            gload_lds16(base + 64 * (16 + jj) + col, buf + 1024 + 256 * k);
        }
        // tier2: rows 32..47, width 32 (512 words @ 1792)
        #pragma unroll
        for (int k = 0; k < 2; ++k) {
            const int w = 256 * k + 4 * lane;
            gload_lds16(base + 64 * (32 + (w >> 5)) + (w & 31), buf + 1792 + 256 * k);
        }
        // tier3: rows 48..63, width 16 (256 words @ 2304)
        {
            const int w = 4 * lane;
            gload_lds16(base + 64 * (48 + (w >> 4)) + (w & 15), buf + 2304);
        }
    } else {
        // rare (~32/16384): g<63 (identity rows) or band tail (crow_v irregular)
        const int  anc = g - 63 + lane;
        const bool vl  = (anc >= 0);
        for (int j = 0; j < 64; ++j) {
            if ((g - 63 + j) < 0 && lane < 64 - j)
                buf[row_start(j) + lane] = 0.0f;     // identity row: zero off-diag
        }
        asm volatile("s_waitcnt lgkmcnt(0)" ::: "memory");  // zeros land before DMA
        int rowbase = 0;
        if (vl) rowbase = crow_v[anc];
        for (int j = 0; j < 64; ++j) {
            const int rbj = __builtin_amdgcn_readlane(rowbase, j);
            if ((g - 63 + j) >= 0 && lane < 64 - j)
                gload_lds4(Vv + rbj + lane, buf + row_start(j));
        }
    }
}

__global__ __launch_bounds__(64) void gp_solve_kernel(
    const float* __restrict__ Uv,
    const float* __restrict__ Vv,
    const float* __restrict__ mean,
    const float* __restrict__ mean_post,
    const float* __restrict__ y,
    const int*   __restrict__ gidx,
    const int*   __restrict__ crow_u,
    const int*   __restrict__ crow_v,
    const float* __restrict__ noise,
    float*       __restrict__ partial)
{
    __shared__ __align__(16) float buf[kTileW];   // ONE buffer: tile is dead
                                                  // once v[] regs are loaded.
    const int lane  = (int)threadIdx.x;
    const int bbase = (int)blockIdx.x * kEPB;

    const float inv2n = 0.5f / noise[0];
    int gcur = gidx[bbase];
    stage_tile(gcur, lane, buf, Vv, crow_v);       // pipeline prologue
    asm volatile("s_waitcnt vmcnt(0)" ::: "memory");

    float accum = 0.0f;

    #pragma unroll 1
    for (int e = 0; e < kEPB; ++e) {
        // ---- early loads for current element (+ next g), hidden under sweep ----
        const int gnext = (e < kEPB - 1) ? gidx[bbase + e + 1] : 63;
        const int  anc = gcur - 63 + lane;
        const bool vl  = (anc >= 0);
        const int  L   = (gcur + 1 < 64) ? (gcur + 1) : 64;
        const int  ub  = (gcur >= 63) ? (2016 + 64 * (gcur - 63)) : crow_u[gcur];
        float uval = 0.0f, md = 0.0f;
        if (vl) {
            uval = Uv[ub + lane - (64 - L)];       // row gcur of U, last L slots
            md   = mean[anc] - mean_post[anc];
        }
        const float yv  = y[gcur];
        const float mpv = mean_post[gcur];

        // ---- pull tile into registers (pre-scaled by 1/diag) ----
        const int rs = row_start(lane);
        const float d0   = buf[rs];
        const float diag = vl ? d0 : 1.0f;         // identity rows: unit diagonal
        const float invd = 1.0f / diag;
        // v[i] = V_sub[lane][i]/diag for i>=lane; i<lane reads prior rows'
        // garbage, provably unused before this lane's residual is consumed.
        const float* vrow = buf + (rs - lane);
        float v[64];
        #pragma unroll
        for (int i = 0; i < 64; i += 2) {
            const float a0 = vrow[i];
            const float a1 = vrow[i + 1];
            v[i]     = a0 * invd;
            v[i + 1] = a1 * invd;
        }
        // all ds_reads drained -> buf is dead; restage it for the next element
        asm volatile("s_waitcnt lgkmcnt(0)" ::: "memory");
        if (e < kEPB - 1)
            stage_tile(gnext, lane, buf, Vv, crow_v);
        __builtin_amdgcn_sched_barrier(0);         // pin: stage issues before sweep

        // ---- pre-scaled dual-RHS back-substitution (unit diagonal) ----
        float r_e = (lane == 63) ? invd : 0.0f;    // D^-1 e_{63}
        float r_u = uval * invd;                   // D^-1 U_sub
        float acc_e = 0.0f, acc_u = 0.0f;
        #pragma unroll
        for (int i = 63; i >= 0; --i) {
            const float s_e = bcastf(r_e, i);      // x_i for RHS e
            const float s_u = bcastf(r_u, i);      // x_i for RHS u
            r_e = fmaf(-v[i], s_e, r_e);           // on lane i: v[i]=1 -> r=0
            r_u = fmaf(-v[i], s_u, r_u);
            acc_e = fmaf(s_e, s_e, acc_e);
            acc_u = fmaf(s_u, s_u, acc_u);
        }

        // ---- dot(U_sub, md) via wave reduction ----
        float dot = uval * md;
        #pragma unroll
        for (int m = 1; m < 64; m <<= 1)
            dot += __shfl_xor(dot, m, 64);

        const float ulast  = bcastf(uval, 63);     // U_values[crow_u[g+1]-1]
        const float vfirst = bcastf(diag, 63);     // V_values[crow_v[g]]
        const float resid  = yv - mpv;
        accum += __logf(ulast) - __logf(vfirst)
               - 0.5f * dot * dot
               - 0.5f * acc_u
               - (resid * resid + acc_e) * inv2n;

        // next element's tile (10 DMAs) fully landed; nothing else outstanding
        asm volatile("s_waitcnt vmcnt(0)" ::: "memory");
        gcur = gnext;
    }

    if (lane == 0)
        partial[blockIdx.x] = accum;
}

__global__ __launch_bounds__(1024) void gp_reduce_kernel(
    const float* __restrict__ partial,
    const float* __restrict__ noise,
    float*       __restrict__ out)
{
    __shared__ float ws[16];
    const int t = (int)threadIdx.x;
    const float4 p = reinterpret_cast<const float4*>(partial)[t];   // 1024*4 = 4096
    float a = (p.x + p.y) + (p.z + p.w);
    #pragma unroll
    for (int m = 1; m < 64; m <<= 1)
        a += __shfl_xor(a, m, 64);
    if ((t & 63) == 0) ws[t >> 6] = a;
    __syncthreads();
    if (t == 0) {
        float tot = 0.0f;
        #pragma unroll
        for (int k = 0; k < 16; ++k) tot += ws[k];
        tot += -0.5f * (float)kB * logf(2.0f * 3.14159265358979323846f * noise[0]);
        out[0] = tot;
    }
}

extern "C" void kernel_launch(void* const* d_in, const int* in_sizes, int n_in,
                              void* d_out, int out_size, void* d_ws, size_t ws_size,
                              hipStream_t stream)
{
    const float* Uv        = (const float*)d_in[0];
    const float* Vv        = (const float*)d_in[1];
    const float* mean      = (const float*)d_in[2];
    const float* mean_post = (const float*)d_in[3];
    const float* y         = (const float*)d_in[4];
    const float* noise     = (const float*)d_in[5];
    const int*   gidx      = (const int*)d_in[6];
    const int*   crow_u    = (const int*)d_in[7];
    const int*   crow_v    = (const int*)d_in[8];
    float* partial = (float*)d_ws;   // kBlocks = 4096 floats

    gp_solve_kernel<<<dim3(kBlocks), dim3(64), 0, stream>>>(
        Uv, Vv, mean, mean_post, y, gidx, crow_u, crow_v, noise, partial);
    gp_reduce_kernel<<<dim3(1), dim3(1024), 0, stream>>>(
        partial, noise, (float*)d_out);
}